// Round 5
// baseline (352.567 us; speedup 1.0000x reference)
//
#include <hip/hip_runtime.h>

// MultiBoxLoss_four_corners — B=64, P=8732, C=81, NEG_POS_RATIO=3
// Outputs: (loss_l/N, loss_c/N, loss_four_corners/N) -> d_out[0..2] (f32)
//
// R7: all prior variants (107-188us) kept per-row gather structure -> short
// dependent load chains, SIMDs idle (VALU<=23%, HBM<=19%). Now k_main is a
// two-phase block: Phase A streams the block's contiguous 128-row conf span
// as 11 unrolled clamped float4 loads/thread (register-staged, ~11KB in
// flight/wave, copy-kernel shape), exp on arrival -> LDS. Phase B: one sync,
// 2 threads/row sum 81 exps from LDS (2 lanes/bank = free), shfl, log,
// minus row[tgt] prefetched at kernel start. No barriers in hot path.

#define NB 64
#define NP 8732
#define NC 81
constexpr int BP = NB * NP;               // 558848
constexpr int RB = 128;                   // rows per k_main block
constexpr int RBLK = (NP + RB - 1) / RB;  // 69 (68 full + tail 28)
constexpr int NCHF = RB * NC / 4;         // 2592 float4 chunks (full block)
constexpr int NITER = (NCHF + 255) / 256; // 11

__device__ inline float sl1(float d) {
    d = fabsf(d);
    return d < 1.0f ? 0.5f * d * d : d - 0.5f;
}

// ws layout: ce[BP] | acc[2] | npos_b[64](int) | spos_b[64] | sneg_b[64] | loss_c_b[64]
__global__ void k_init(float* acc_area) {
    if (threadIdx.x < 194) acc_area[threadIdx.x] = 0.0f;
}

__global__ __launch_bounds__(256) void k_main(
    const float* __restrict__ loc_data, const float* __restrict__ conf_data,
    const float* __restrict__ fc_data,  const float* __restrict__ loc_t,
    const float* __restrict__ fc_t,     const int* __restrict__ conf_t,
    float* __restrict__ ce, float* __restrict__ acc,
    int* __restrict__ npos_b, float* __restrict__ spos_b, float* __restrict__ sneg_b)
{
    const int b  = blockIdx.y;
    const int t  = threadIdx.x;
    const int p0 = blockIdx.x * RB;
    const int rs = min(RB, NP - p0);          // 128 or 28 (tail)
    const int nch = rs * NC / 4;              // 2592 or 567 (exact)

    __shared__ __align__(16) float4 ex4[NCHF];   // 41.5 KB exp'd conf
    __shared__ float red[4][5];

    float l_sum = 0.0f, f_sum = 0.0f, sp = 0.0f, sn = 0.0f;
    int np = 0;

    // ---- issue order matters: oldest-first so later waits don't drain ----
    // (1) phase-B target row: pair-sub0 thread loads its row's conf_t FIRST
    const int r = t >> 1, sub = t & 1;
    const bool browner = (sub == 0) && (r < rs);
    size_t gr = 0; int tr = 0;
    if (browner) {
        gr = (size_t)b * NP + (size_t)(p0 + r);
        tr = conf_t[gr];                                   // load #1 (oldest)
    }

    // (2) smooth-L1 loads (t < RB)
    const int p = p0 + t;
    int tgt = 0;
    float4 a4{}, a4t{}, c0{}, c1{}, d0{}, d1{};
    const bool slact = (t < RB) && (p < NP);
    if (slact) {
        const size_t g = (size_t)b * NP + p;
        tgt = conf_t[g];
        a4  = ((const float4*)loc_data)[g];
        a4t = ((const float4*)loc_t)[g];
        c0  = ((const float4*)fc_data)[2 * g];
        c1  = ((const float4*)fc_data)[2 * g + 1];
        d0  = ((const float4*)fc_t)[2 * g];
        d1  = ((const float4*)fc_t)[2 * g + 1];
    }

    // (3) phase A: 11 clamped back-to-back float4 streaming loads
    // block span start: (b*NP + p0)*81 floats; NP*81 and RB*81 are mult of 4
    const float4* src4 = (const float4*)conf_data + ((size_t)b * NP + p0) * NC / 4;
    float4 vbuf[NITER];
    #pragma unroll
    for (int k = 0; k < NITER; ++k) {
        int idx = t + (k << 8);
        idx = idx < nch ? idx : nch - 1;                   // clamp: dup-load
        vbuf[k] = src4[idx];
    }

    // (4) tv gather (waits only load #1 — 18 newer loads keep flying)
    float tv = 0.0f;
    if (browner) tv = conf_data[gr * NC + (size_t)tr];

    // (5) smooth-L1 compute (waits loads #2-7)
    if (slact) {
        const float posf = (tgt > 0) ? 1.0f : 0.0f;
        np = (tgt > 0) ? 1 : 0;
        l_sum = (sl1(a4.x - a4t.x) + sl1(a4.y - a4t.y) +
                 sl1(a4.z - a4t.z) + sl1(a4.w - a4t.w)) * posf;
        f_sum = (sl1(c0.x - d0.x) + sl1(c0.y - d0.y) + sl1(c0.z - d0.z) + sl1(c0.w - d0.w) +
                 sl1(c1.x - d1.x) + sl1(c1.y - d1.y) + sl1(c1.z - d1.z) + sl1(c1.w - d1.w)) * posf;
    }

    // (6) phase A compute: exp on arrival (vmcnt staircase), LDS b128 writes
    #pragma unroll
    for (int k = 0; k < NITER; ++k) {
        int idx = t + (k << 8);
        idx = idx < nch ? idx : nch - 1;                   // dup-write same val
        const float4 v = vbuf[k];
        float4 e;
        e.x = __expf(v.x); e.y = __expf(v.y);
        e.z = __expf(v.z); e.w = __expf(v.w);
        ex4[idx] = e;
    }

    __syncthreads();

    // ---- phase B: 2 threads per row, sum 81 exps from LDS ----
    // lane pair (r, sub): sub0 sums i=0..40, sub1 i=41..80; banks: 2 lanes/bank (free)
    if (r < rs) {
        const float* exf = (const float*)ex4 + r * NC;
        float s0 = 0.0f, s1 = 0.0f;
        const int i0 = sub * 41;                           // 41 or 40 elems
        const int cnt = 41 - sub;
        for (int i = 0; i < 40; i += 2) {                  // 20x2 unrolled pairs
            s0 += exf[i0 + i];
            s1 += exf[i0 + i + 1];
        }
        if (cnt == 41) s0 += exf[i0 + 40];
        float ss = s0 + s1;
        ss += __shfl_xor(ss, 1, 64);                       // pair combine
        if (browner) {
            const float cev = __logf(ss) - tv;
            ce[gr] = cev;
            if (tr > 0) sp += cev; else sn += cev;
        }
    }

    // ---- block reduce 5 values -> atomics ----
    const int wave = t >> 6, lane = t & 63;
    float vnp = (float)np;
    #pragma unroll
    for (int o = 32; o; o >>= 1) {
        l_sum += __shfl_xor(l_sum, o, 64);
        f_sum += __shfl_xor(f_sum, o, 64);
        sp    += __shfl_xor(sp, o, 64);
        sn    += __shfl_xor(sn, o, 64);
        vnp   += __shfl_xor(vnp, o, 64);
    }
    if (lane == 0) {
        red[wave][0] = l_sum; red[wave][1] = f_sum;
        red[wave][2] = sp;    red[wave][3] = sn;   red[wave][4] = vnp;
    }
    __syncthreads();
    if (t == 0) {
        float rl = 0, rf = 0, rp = 0, rn = 0, rc = 0;
        #pragma unroll
        for (int w = 0; w < 4; ++w) {
            rl += red[w][0]; rf += red[w][1]; rp += red[w][2];
            rn += red[w][3]; rc += red[w][4];
        }
        atomicAdd(&acc[0], rl);
        atomicAdd(&acc[1], rf);
        atomicAdd(&spos_b[b], rp);
        atomicAdd(&sneg_b[b], rn);
        atomicAdd(&npos_b[b], (int)rc);
    }
}

// One block per batch. Common path: O(1). Rare path: top-K via bit binary search.
__global__ __launch_bounds__(256) void k_batch(
    const float* __restrict__ ce, const int* __restrict__ conf_t,
    const int* __restrict__ npos_b, const float* __restrict__ spos_b,
    const float* __restrict__ sneg_b, float* __restrict__ loss_c_b)
{
    const int b = blockIdx.x;
    const int t = threadIdx.x;
    const int npos    = npos_b[b];
    const int nneg    = NP - npos;
    const int num_neg = min(3 * npos, NP - 1);

    if (num_neg >= nneg) {              // all negatives selected (this dataset)
        if (t == 0) loss_c_b[b] = spos_b[b] + sneg_b[b];
        return;
    }
    if (num_neg <= 0) {
        if (t == 0) loss_c_b[b] = spos_b[b];
        return;
    }

    // general path: stage negative CE into LDS (positives -> -1), top-K sum
    __shared__ float ce_s[NP];
    __shared__ float sredf[4];
    __shared__ int   sredi[4];
    const float* crow = ce + (size_t)b * NP;
    const int*   trow = conf_t + (size_t)b * NP;
    for (int p = t; p < NP; p += 256)
        ce_s[p] = (trow[p] > 0) ? -1.0f : crow[p];
    __syncthreads();

    const int wave = t >> 6, lane = t & 63;
    const int K = num_neg;
    unsigned lo = 0u, hi = 0x7f800000u;
    while (lo < hi) {
        unsigned mid = lo + ((hi - lo) >> 1);
        float v = __uint_as_float(mid);
        int c_t = 0;
        for (int p = t; p < NP; p += 256) c_t += (ce_s[p] > v) ? 1 : 0;
        #pragma unroll
        for (int o = 32; o; o >>= 1) c_t += __shfl_xor(c_t, o, 64);
        __syncthreads();
        if (lane == 0) sredi[wave] = c_t;
        __syncthreads();
        int cnt = sredi[0] + sredi[1] + sredi[2] + sredi[3];
        if (cnt < K) hi = mid; else lo = mid + 1;
    }
    float v = __uint_as_float(lo);       // K-th largest negative CE
    int c_t = 0; float s_t = 0.0f;
    for (int p = t; p < NP; p += 256) {
        float x = ce_s[p];
        if (x > v) { c_t++; s_t += x; }
    }
    #pragma unroll
    for (int o = 32; o; o >>= 1) {
        c_t += __shfl_xor(c_t, o, 64);
        s_t += __shfl_xor(s_t, o, 64);
    }
    __syncthreads();
    if (lane == 0) { sredi[wave] = c_t; sredf[wave] = s_t; }
    __syncthreads();
    if (t == 0) {
        int   cnt = sredi[0] + sredi[1] + sredi[2] + sredi[3];
        float sgt = sredf[0] + sredf[1] + sredf[2] + sredf[3];
        loss_c_b[b] = spos_b[b] + sgt + (float)(K - cnt) * v;
    }
}

__global__ void k_final(const float* __restrict__ acc,
                        const float* __restrict__ loss_c_b,
                        const int* __restrict__ npos_b,
                        float* __restrict__ out)
{
    const int t = threadIdx.x;           // 64 threads
    float lc = loss_c_b[t];
    int   np = npos_b[t];
    #pragma unroll
    for (int o = 32; o; o >>= 1) {
        lc += __shfl_xor(lc, o, 64);
        np += __shfl_xor(np, o, 64);
    }
    if (t == 0) {
        float N = (float)np;
        out[0] = acc[0] / N;
        out[1] = lc / N;
        out[2] = acc[1] / N;
    }
}

extern "C" void kernel_launch(void* const* d_in, const int* in_sizes, int n_in,
                              void* d_out, int out_size, void* d_ws, size_t ws_size,
                              hipStream_t stream)
{
    const float* loc_data  = (const float*)d_in[0];
    const float* conf_data = (const float*)d_in[1];
    const float* fc_data   = (const float*)d_in[2];
    const float* loc_t     = (const float*)d_in[3];
    const float* fc_t      = (const float*)d_in[4];
    const int*   conf_t    = (const int*)d_in[5];
    float* out = (float*)d_out;

    float* ce       = (float*)d_ws;
    float* acc      = ce + BP;           // [2]
    int*   npos_b   = (int*)(acc + 2);   // [64]
    float* spos_b   = (float*)(npos_b + 64);
    float* sneg_b   = spos_b + 64;
    float* loss_c_b = sneg_b + 64;

    hipLaunchKernelGGL(k_init,  dim3(1), dim3(256), 0, stream, acc);
    hipLaunchKernelGGL(k_main,  dim3(RBLK, NB), dim3(256), 0, stream,
                       loc_data, conf_data, fc_data, loc_t, fc_t, conf_t,
                       ce, acc, npos_b, spos_b, sneg_b);
    hipLaunchKernelGGL(k_batch, dim3(NB), dim3(256), 0, stream,
                       ce, conf_t, npos_b, spos_b, sneg_b, loss_c_b);
    hipLaunchKernelGGL(k_final, dim3(1), dim3(64), 0, stream,
                       acc, loss_c_b, npos_b, out);
}

// Round 6
// 305.211 us; speedup vs baseline: 1.1552x; 1.1552x over previous
//
#include <hip/hip_runtime.h>

// MultiBoxLoss_four_corners — B=64, P=8732, C=81, NEG_POS_RATIO=3
// Outputs: (loss_l/N, loss_c/N, loss_four_corners/N) -> d_out[0..2] (f32)
//
// R8: diagnosis — all R2-R7 variants (107-188us) share a ~110us floor that is
// INSENSITIVE to memory residence (warm-L3 replays run at identical speed) and
// to kernel structure. The shared invariant: every block ends with atomicAdd
// to the SAME global words (acc[0..1] + 4 shared cache lines of per-b slots);
// ~11K same-line device-scope RMWs from 8 XCDs serialize on fabric coherence
// (~25-50ns each ~= 100-200us). This round: ZERO cross-block atomics. Each
// block stores 5 partials to a private slot part[b][bx][5]; k_batch reduces
// 35 slots/batch (1 shfl-wave); k_final reduces 64 batches. CE path kept
// byte-identical to R6 (4 lanes/row, direct float4) for clean attribution.

#define NB 64
#define NP 8732
#define NC 81
constexpr int BP = NB * NP;              // 558848
constexpr int PBLK = (NP + 255) / 256;   // 35 blocks per batch (tail 28)
constexpr unsigned MAXCH = (unsigned)((size_t)BP * NC / 4 - 1);  // 11316671

__device__ inline float sl1(float d) {
    d = fabsf(d);
    return d < 1.0f ? 0.5f * d * d : d - 0.5f;
}

// ws layout (floats): ce[BP] | part[NB*PBLK*5] | loss_c_b[64] | npos_b[64](int)
//                     | lsum_b[64] | fsum_b[64]

__global__ __launch_bounds__(256) void k_main(
    const float* __restrict__ loc_data, const float* __restrict__ conf_data,
    const float* __restrict__ fc_data,  const float* __restrict__ loc_t,
    const float* __restrict__ fc_t,     const int* __restrict__ conf_t,
    float* __restrict__ ce, float* __restrict__ part)
{
    const int b  = blockIdx.y;
    const int bx = blockIdx.x;
    const int t  = threadIdx.x;
    const int p0 = bx << 8;

    __shared__ int   tgt_s[256];
    __shared__ float red[4][5];

    float l_sum = 0.0f, f_sum = 0.0f, sp = 0.0f, sn = 0.0f;
    int np = 0;

    // ---- per-prior smooth-L1 (coalesced float4) + stash targets ----
    {
        const int p = p0 + t;
        int tgt = 0;
        if (p < NP) {
            const size_t g = (size_t)b * NP + p;
            tgt = conf_t[g];
            const float posf = (tgt > 0) ? 1.0f : 0.0f;
            np = (tgt > 0) ? 1 : 0;
            float4 a4  = ((const float4*)loc_data)[g];
            float4 a4t = ((const float4*)loc_t)[g];
            l_sum = (sl1(a4.x - a4t.x) + sl1(a4.y - a4t.y) +
                     sl1(a4.z - a4t.z) + sl1(a4.w - a4t.w)) * posf;
            float4 c0 = ((const float4*)fc_data)[2 * g];
            float4 c1 = ((const float4*)fc_data)[2 * g + 1];
            float4 d0 = ((const float4*)fc_t)[2 * g];
            float4 d1 = ((const float4*)fc_t)[2 * g + 1];
            f_sum = (sl1(c0.x - d0.x) + sl1(c0.y - d0.y) + sl1(c0.z - d0.z) + sl1(c0.w - d0.w) +
                     sl1(c1.x - d1.x) + sl1(c1.y - d1.y) + sl1(c1.z - d1.z) + sl1(c1.w - d1.w)) * posf;
        }
        tgt_s[t] = tgt;
    }
    __syncthreads();

    // ---- CE: 4 lanes per row, direct float4 loads (identical to R6) ----
    const int wave = t >> 6, lane = t & 63;
    const int grp = lane >> 2, sub = lane & 3;
    const float4* conf4 = (const float4*)conf_data;

    #pragma unroll 1
    for (int s = 0; s < 4; ++s) {
        const int pl = (wave << 6) + (s << 4) + grp;   // [0,256)
        const int p  = p0 + pl;
        const int pe = min(p, NP - 1);                 // clamp tail reads
        const unsigned g  = (unsigned)b * NP + (unsigned)pe;   // <= 558847
        const unsigned fb = g * (unsigned)NC;          // <= 45266607
        const int al      = (int)(fb & 3u);
        const unsigned c0 = fb >> 2;

        const int tgt = tgt_s[pl];
        float tv = 0.0f;
        if (sub == 0) tv = conf_data[fb + (unsigned)tgt];   // early, L1-hit

        float e = 0.0f;
        #pragma unroll
        for (int k = 0; k < 6; ++k) {
            unsigned ch = c0 + (unsigned)(sub + 4 * k);
            ch = ch > MAXCH ? MAXCH : ch;              // tensor-end clamp
            const float4 v = conf4[ch];
            const int bi = 4 * (sub + 4 * k) - al;     // row elem of v.x
            e += ((unsigned)(bi + 0) < 81u) ? __expf(v.x) : 0.0f;
            e += ((unsigned)(bi + 1) < 81u) ? __expf(v.y) : 0.0f;
            e += ((unsigned)(bi + 2) < 81u) ? __expf(v.z) : 0.0f;
            e += ((unsigned)(bi + 3) < 81u) ? __expf(v.w) : 0.0f;
        }
        e += __shfl_xor(e, 1, 64);                     // 4-lane group sum
        e += __shfl_xor(e, 2, 64);

        if (sub == 0 && p < NP) {
            const float cev = __logf(e) - tv;
            ce[g] = cev;
            if (tgt > 0) sp += cev; else sn += cev;
        }
    }

    // ---- block reduce 5 values -> PRIVATE slot (no atomics) ----
    float vnp = (float)np;
    #pragma unroll
    for (int o = 32; o; o >>= 1) {
        l_sum += __shfl_xor(l_sum, o, 64);
        f_sum += __shfl_xor(f_sum, o, 64);
        sp    += __shfl_xor(sp, o, 64);
        sn    += __shfl_xor(sn, o, 64);
        vnp   += __shfl_xor(vnp, o, 64);
    }
    if (lane == 0) {
        red[wave][0] = l_sum; red[wave][1] = f_sum;
        red[wave][2] = sp;    red[wave][3] = sn;   red[wave][4] = vnp;
    }
    __syncthreads();
    if (t == 0) {
        float rl = 0, rf = 0, rp = 0, rn = 0, rc = 0;
        #pragma unroll
        for (int w = 0; w < 4; ++w) {
            rl += red[w][0]; rf += red[w][1]; rp += red[w][2];
            rn += red[w][3]; rc += red[w][4];
        }
        float* pp = part + ((size_t)b * PBLK + bx) * 5;
        pp[0] = rl; pp[1] = rf; pp[2] = rp; pp[3] = rn; pp[4] = rc;
    }
}

// One block per batch: reduce 35 partial slots, then mining path.
__global__ __launch_bounds__(256) void k_batch(
    const float* __restrict__ ce, const int* __restrict__ conf_t,
    const float* __restrict__ part, float* __restrict__ loss_c_b,
    int* __restrict__ npos_b, float* __restrict__ lsum_b, float* __restrict__ fsum_b)
{
    const int b = blockIdx.x;
    const int t = threadIdx.x;
    __shared__ float hdr[3];                  // spos, sneg, nposf

    if (t < 64) {                             // wave 0 reduces 35 slots
        float v0 = 0, v1 = 0, v2 = 0, v3 = 0, v4 = 0;
        if (t < PBLK) {
            const float* pp = part + ((size_t)b * PBLK + t) * 5;
            v0 = pp[0]; v1 = pp[1]; v2 = pp[2]; v3 = pp[3]; v4 = pp[4];
        }
        #pragma unroll
        for (int o = 32; o; o >>= 1) {
            v0 += __shfl_xor(v0, o, 64);
            v1 += __shfl_xor(v1, o, 64);
            v2 += __shfl_xor(v2, o, 64);
            v3 += __shfl_xor(v3, o, 64);
            v4 += __shfl_xor(v4, o, 64);
        }
        if (t == 0) {
            lsum_b[b] = v0; fsum_b[b] = v1;
            npos_b[b] = (int)v4;
            hdr[0] = v2; hdr[1] = v3; hdr[2] = v4;
        }
    }
    __syncthreads();

    const float spos = hdr[0], sneg = hdr[1];
    const int npos    = (int)hdr[2];
    const int nneg    = NP - npos;
    const int num_neg = min(3 * npos, NP - 1);

    if (num_neg >= nneg) {              // all negatives selected (this dataset)
        if (t == 0) loss_c_b[b] = spos + sneg;
        return;
    }
    if (num_neg <= 0) {
        if (t == 0) loss_c_b[b] = spos;
        return;
    }

    // general path: stage negative CE into LDS (positives -> -1), top-K sum
    __shared__ float ce_s[NP];
    __shared__ float sredf[4];
    __shared__ int   sredi[4];
    const float* crow = ce + (size_t)b * NP;
    const int*   trow = conf_t + (size_t)b * NP;
    for (int p = t; p < NP; p += 256)
        ce_s[p] = (trow[p] > 0) ? -1.0f : crow[p];
    __syncthreads();

    const int wave = t >> 6, lane = t & 63;
    const int K = num_neg;
    unsigned lo = 0u, hi = 0x7f800000u;
    while (lo < hi) {
        unsigned mid = lo + ((hi - lo) >> 1);
        float v = __uint_as_float(mid);
        int c_t = 0;
        for (int p = t; p < NP; p += 256) c_t += (ce_s[p] > v) ? 1 : 0;
        #pragma unroll
        for (int o = 32; o; o >>= 1) c_t += __shfl_xor(c_t, o, 64);
        __syncthreads();
        if (lane == 0) sredi[wave] = c_t;
        __syncthreads();
        int cnt = sredi[0] + sredi[1] + sredi[2] + sredi[3];
        if (cnt < K) hi = mid; else lo = mid + 1;
    }
    float v = __uint_as_float(lo);       // K-th largest negative CE
    int c_t = 0; float s_t = 0.0f;
    for (int p = t; p < NP; p += 256) {
        float x = ce_s[p];
        if (x > v) { c_t++; s_t += x; }
    }
    #pragma unroll
    for (int o = 32; o; o >>= 1) {
        c_t += __shfl_xor(c_t, o, 64);
        s_t += __shfl_xor(s_t, o, 64);
    }
    __syncthreads();
    if (lane == 0) { sredi[wave] = c_t; sredf[wave] = s_t; }
    __syncthreads();
    if (t == 0) {
        int   cnt = sredi[0] + sredi[1] + sredi[2] + sredi[3];
        float sgt = sredf[0] + sredf[1] + sredf[2] + sredf[3];
        loss_c_b[b] = spos + sgt + (float)(K - cnt) * v;
    }
}

__global__ void k_final(const float* __restrict__ loss_c_b,
                        const int* __restrict__ npos_b,
                        const float* __restrict__ lsum_b,
                        const float* __restrict__ fsum_b,
                        float* __restrict__ out)
{
    const int t = threadIdx.x;           // 64 threads
    float lc = loss_c_b[t];
    float ls = lsum_b[t];
    float fs = fsum_b[t];
    int   np = npos_b[t];
    #pragma unroll
    for (int o = 32; o; o >>= 1) {
        lc += __shfl_xor(lc, o, 64);
        ls += __shfl_xor(ls, o, 64);
        fs += __shfl_xor(fs, o, 64);
        np += __shfl_xor(np, o, 64);
    }
    if (t == 0) {
        float N = (float)np;
        out[0] = ls / N;
        out[1] = lc / N;
        out[2] = fs / N;
    }
}

extern "C" void kernel_launch(void* const* d_in, const int* in_sizes, int n_in,
                              void* d_out, int out_size, void* d_ws, size_t ws_size,
                              hipStream_t stream)
{
    const float* loc_data  = (const float*)d_in[0];
    const float* conf_data = (const float*)d_in[1];
    const float* fc_data   = (const float*)d_in[2];
    const float* loc_t     = (const float*)d_in[3];
    const float* fc_t      = (const float*)d_in[4];
    const int*   conf_t    = (const int*)d_in[5];
    float* out = (float*)d_out;

    float* ce       = (float*)d_ws;
    float* part     = ce + BP;                 // [NB*PBLK*5] = 11200
    float* loss_c_b = part + NB * PBLK * 5;    // [64]
    int*   npos_b   = (int*)(loss_c_b + 64);   // [64]
    float* lsum_b   = (float*)(npos_b + 64);   // [64]
    float* fsum_b   = lsum_b + 64;             // [64]

    hipLaunchKernelGGL(k_main,  dim3(PBLK, NB), dim3(256), 0, stream,
                       loc_data, conf_data, fc_data, loc_t, fc_t, conf_t,
                       ce, part);
    hipLaunchKernelGGL(k_batch, dim3(NB), dim3(256), 0, stream,
                       ce, conf_t, part, loss_c_b, npos_b, lsum_b, fsum_b);
    hipLaunchKernelGGL(k_final, dim3(1), dim3(64), 0, stream,
                       loss_c_b, npos_b, lsum_b, fsum_b, out);
}

// Round 7
// 299.977 us; speedup vs baseline: 1.1753x; 1.0174x over previous
//
#include <hip/hip_runtime.h>

// MultiBoxLoss_four_corners — B=64, P=8732, C=81, NEG_POS_RATIO=3
// Outputs: (loss_l/N, loss_c/N, loss_four_corners/N) -> d_out[0..2] (f32)
//
// R9: attribution split + MLP push. k_main (~100us) split into:
//   k_sl1 — 56 MB loc/fc/targets streams (pure coalesced float4)
//   k_ce  — 181 MB conf: 4 lanes/row, DEPTH-2 software pipeline (two named
//           register buffers, 12 dwordx4 in flight; stage s+1 issued before
//           stage s computes) and row[tgt] extracted IN-REGISTER from the
//           loaded chunks (bi==tgt select + same shfl combine) — the
//           uncoalesced gather load is gone.
// No cross-block atomics (R8). k_batch reduces partS/partC slots.

#define NB 64
#define NP 8732
#define NC 81
constexpr int BP = NB * NP;              // 558848
constexpr int PBLK = (NP + 255) / 256;   // 35 blocks per batch (tail 28)
constexpr unsigned MAXCH = (unsigned)((size_t)BP * NC / 4 - 1);  // 11316671

__device__ inline float sl1(float d) {
    d = fabsf(d);
    return d < 1.0f ? 0.5f * d * d : d - 0.5f;
}

// ws layout (floats): ce[BP] | partS[NB*PBLK*4] | partC[NB*PBLK*2]
//                     | loss_c_b[64] | npos_b[64](int) | lsum_b[64] | fsum_b[64]

// ---------- smooth-L1 + npos: 7 coalesced streams, one prior/thread ----------
__global__ __launch_bounds__(256) void k_sl1(
    const float* __restrict__ loc_data, const float* __restrict__ fc_data,
    const float* __restrict__ loc_t,    const float* __restrict__ fc_t,
    const int* __restrict__ conf_t,     float* __restrict__ partS)
{
    const int b  = blockIdx.y;
    const int bx = blockIdx.x;
    const int t  = threadIdx.x;
    const int p  = (bx << 8) + t;

    __shared__ float red[4][3];
    float l_sum = 0.0f, f_sum = 0.0f;
    int np = 0;

    if (p < NP) {
        const size_t g = (size_t)b * NP + p;
        const int tgt = conf_t[g];
        const float posf = (tgt > 0) ? 1.0f : 0.0f;
        np = (tgt > 0) ? 1 : 0;
        float4 a4  = ((const float4*)loc_data)[g];
        float4 a4t = ((const float4*)loc_t)[g];
        float4 c0  = ((const float4*)fc_data)[2 * g];
        float4 c1  = ((const float4*)fc_data)[2 * g + 1];
        float4 d0  = ((const float4*)fc_t)[2 * g];
        float4 d1  = ((const float4*)fc_t)[2 * g + 1];
        l_sum = (sl1(a4.x - a4t.x) + sl1(a4.y - a4t.y) +
                 sl1(a4.z - a4t.z) + sl1(a4.w - a4t.w)) * posf;
        f_sum = (sl1(c0.x - d0.x) + sl1(c0.y - d0.y) + sl1(c0.z - d0.z) + sl1(c0.w - d0.w) +
                 sl1(c1.x - d1.x) + sl1(c1.y - d1.y) + sl1(c1.z - d1.z) + sl1(c1.w - d1.w)) * posf;
    }

    const int wave = t >> 6, lane = t & 63;
    float vnp = (float)np;
    #pragma unroll
    for (int o = 32; o; o >>= 1) {
        l_sum += __shfl_xor(l_sum, o, 64);
        f_sum += __shfl_xor(f_sum, o, 64);
        vnp   += __shfl_xor(vnp, o, 64);
    }
    if (lane == 0) { red[wave][0] = l_sum; red[wave][1] = f_sum; red[wave][2] = vnp; }
    __syncthreads();
    if (t == 0) {
        float rl = 0, rf = 0, rc = 0;
        #pragma unroll
        for (int w = 0; w < 4; ++w) { rl += red[w][0]; rf += red[w][1]; rc += red[w][2]; }
        float* ps = partS + ((size_t)b * PBLK + bx) * 4;
        ps[0] = rl; ps[1] = rf; ps[2] = rc;
    }
}

// ---------- CE: 4 lanes/row, depth-2 pipelined, in-register tgt extract ----------
#define CE_ISSUE(BUF, PV, FBV, S)                                        \
    {                                                                    \
        const int pl = (wave << 6) + ((S) << 4) + grp;                   \
        const int p  = p0 + pl;                                          \
        const int pe = min(p, NP - 1);                                   \
        const unsigned g  = (unsigned)b * NP + (unsigned)pe;             \
        const unsigned fb = g * (unsigned)NC;                            \
        const unsigned c0 = fb >> 2;                                     \
        PV = p; FBV = fb;                                                \
        _Pragma("unroll")                                                \
        for (int k = 0; k < 6; ++k) {                                    \
            unsigned ch = c0 + (unsigned)(sub + 4 * k);                  \
            ch = ch > MAXCH ? MAXCH : ch;                                \
            BUF[k] = conf4[ch];                                         \
        }                                                                \
    }

#define CE_COMPUTE(BUF, PV, FBV, S)                                      \
    {                                                                    \
        const int pl  = (wave << 6) + ((S) << 4) + grp;                  \
        const int tgt = tgt_s[pl];                                       \
        const int al  = (int)(FBV & 3u);                                 \
        float e = 0.0f, tv = 0.0f;                                       \
        _Pragma("unroll")                                                \
        for (int k = 0; k < 6; ++k) {                                    \
            const float4 v = BUF[k];                                     \
            const int bi = 4 * (sub + 4 * k) - al;                       \
            e  += ((unsigned)(bi + 0) < 81u) ? __expf(v.x) : 0.0f;       \
            e  += ((unsigned)(bi + 1) < 81u) ? __expf(v.y) : 0.0f;       \
            e  += ((unsigned)(bi + 2) < 81u) ? __expf(v.z) : 0.0f;       \
            e  += ((unsigned)(bi + 3) < 81u) ? __expf(v.w) : 0.0f;       \
            tv += (bi + 0 == tgt) ? v.x : 0.0f;                          \
            tv += (bi + 1 == tgt) ? v.y : 0.0f;                          \
            tv += (bi + 2 == tgt) ? v.z : 0.0f;                          \
            tv += (bi + 3 == tgt) ? v.w : 0.0f;                          \
        }                                                                \
        e  += __shfl_xor(e, 1, 64);  e  += __shfl_xor(e, 2, 64);         \
        tv += __shfl_xor(tv, 1, 64); tv += __shfl_xor(tv, 2, 64);        \
        if (sub == 0 && PV < NP) {                                       \
            const unsigned g = (unsigned)b * NP + (unsigned)PV;          \
            const float cev = __logf(e) - tv;                            \
            ce[g] = cev;                                                 \
            if (tgt > 0) sp += cev; else sn += cev;                      \
        }                                                                \
    }

__global__ __launch_bounds__(256) void k_ce(
    const float* __restrict__ conf_data, const int* __restrict__ conf_t,
    float* __restrict__ ce, float* __restrict__ partC)
{
    const int b  = blockIdx.y;
    const int bx = blockIdx.x;
    const int t  = threadIdx.x;
    const int p0 = bx << 8;

    __shared__ int   tgt_s[256];
    __shared__ float red[4][2];

    {
        const int p = p0 + t;
        tgt_s[t] = (p < NP) ? conf_t[(size_t)b * NP + p] : 0;
    }
    __syncthreads();

    const int wave = t >> 6, lane = t & 63;
    const int grp = lane >> 2, sub = lane & 3;
    const float4* conf4 = (const float4*)conf_data;
    float sp = 0.0f, sn = 0.0f;

    float4 bufA[6], bufB[6];
    int pA, pB; unsigned fbA, fbB;

    CE_ISSUE(bufA, pA, fbA, 0);
    CE_ISSUE(bufB, pB, fbB, 1);
    CE_COMPUTE(bufA, pA, fbA, 0);
    CE_ISSUE(bufA, pA, fbA, 2);
    CE_COMPUTE(bufB, pB, fbB, 1);
    CE_ISSUE(bufB, pB, fbB, 3);
    CE_COMPUTE(bufA, pA, fbA, 2);
    CE_COMPUTE(bufB, pB, fbB, 3);

    // block reduce sp, sn -> private slot
    #pragma unroll
    for (int o = 32; o; o >>= 1) {
        sp += __shfl_xor(sp, o, 64);
        sn += __shfl_xor(sn, o, 64);
    }
    if (lane == 0) { red[wave][0] = sp; red[wave][1] = sn; }
    __syncthreads();
    if (t == 0) {
        float rp = 0, rn = 0;
        #pragma unroll
        for (int w = 0; w < 4; ++w) { rp += red[w][0]; rn += red[w][1]; }
        float* pc = partC + ((size_t)b * PBLK + bx) * 2;
        pc[0] = rp; pc[1] = rn;
    }
}

// One block per batch: reduce 35 partial slots, then mining path.
__global__ __launch_bounds__(256) void k_batch(
    const float* __restrict__ ce, const int* __restrict__ conf_t,
    const float* __restrict__ partS, const float* __restrict__ partC,
    float* __restrict__ loss_c_b, int* __restrict__ npos_b,
    float* __restrict__ lsum_b, float* __restrict__ fsum_b)
{
    const int b = blockIdx.x;
    const int t = threadIdx.x;
    __shared__ float hdr[3];                  // spos, sneg, nposf

    if (t < 64) {                             // wave 0 reduces 35 slots
        float v0 = 0, v1 = 0, v2 = 0, v3 = 0, v4 = 0;
        if (t < PBLK) {
            const float* ps = partS + ((size_t)b * PBLK + t) * 4;
            v0 = ps[0]; v1 = ps[1]; v4 = ps[2];
            const float* pc = partC + ((size_t)b * PBLK + t) * 2;
            v2 = pc[0]; v3 = pc[1];
        }
        #pragma unroll
        for (int o = 32; o; o >>= 1) {
            v0 += __shfl_xor(v0, o, 64);
            v1 += __shfl_xor(v1, o, 64);
            v2 += __shfl_xor(v2, o, 64);
            v3 += __shfl_xor(v3, o, 64);
            v4 += __shfl_xor(v4, o, 64);
        }
        if (t == 0) {
            lsum_b[b] = v0; fsum_b[b] = v1;
            npos_b[b] = (int)v4;
            hdr[0] = v2; hdr[1] = v3; hdr[2] = v4;
        }
    }
    __syncthreads();

    const float spos = hdr[0], sneg = hdr[1];
    const int npos    = (int)hdr[2];
    const int nneg    = NP - npos;
    const int num_neg = min(3 * npos, NP - 1);

    if (num_neg >= nneg) {              // all negatives selected (this dataset)
        if (t == 0) loss_c_b[b] = spos + sneg;
        return;
    }
    if (num_neg <= 0) {
        if (t == 0) loss_c_b[b] = spos;
        return;
    }

    // general path: stage negative CE into LDS (positives -> -1), top-K sum
    __shared__ float ce_s[NP];
    __shared__ float sredf[4];
    __shared__ int   sredi[4];
    const float* crow = ce + (size_t)b * NP;
    const int*   trow = conf_t + (size_t)b * NP;
    for (int p = t; p < NP; p += 256)
        ce_s[p] = (trow[p] > 0) ? -1.0f : crow[p];
    __syncthreads();

    const int wave = t >> 6, lane = t & 63;
    const int K = num_neg;
    unsigned lo = 0u, hi = 0x7f800000u;
    while (lo < hi) {
        unsigned mid = lo + ((hi - lo) >> 1);
        float v = __uint_as_float(mid);
        int c_t = 0;
        for (int p = t; p < NP; p += 256) c_t += (ce_s[p] > v) ? 1 : 0;
        #pragma unroll
        for (int o = 32; o; o >>= 1) c_t += __shfl_xor(c_t, o, 64);
        __syncthreads();
        if (lane == 0) sredi[wave] = c_t;
        __syncthreads();
        int cnt = sredi[0] + sredi[1] + sredi[2] + sredi[3];
        if (cnt < K) hi = mid; else lo = mid + 1;
    }
    float v = __uint_as_float(lo);       // K-th largest negative CE
    int c_t = 0; float s_t = 0.0f;
    for (int p = t; p < NP; p += 256) {
        float x = ce_s[p];
        if (x > v) { c_t++; s_t += x; }
    }
    #pragma unroll
    for (int o = 32; o; o >>= 1) {
        c_t += __shfl_xor(c_t, o, 64);
        s_t += __shfl_xor(s_t, o, 64);
    }
    __syncthreads();
    if (lane == 0) { sredi[wave] = c_t; sredf[wave] = s_t; }
    __syncthreads();
    if (t == 0) {
        int   cnt = sredi[0] + sredi[1] + sredi[2] + sredi[3];
        float sgt = sredf[0] + sredf[1] + sredf[2] + sredf[3];
        loss_c_b[b] = spos + sgt + (float)(K - cnt) * v;
    }
}

__global__ void k_final(const float* __restrict__ loss_c_b,
                        const int* __restrict__ npos_b,
                        const float* __restrict__ lsum_b,
                        const float* __restrict__ fsum_b,
                        float* __restrict__ out)
{
    const int t = threadIdx.x;           // 64 threads
    float lc = loss_c_b[t];
    float ls = lsum_b[t];
    float fs = fsum_b[t];
    int   np = npos_b[t];
    #pragma unroll
    for (int o = 32; o; o >>= 1) {
        lc += __shfl_xor(lc, o, 64);
        ls += __shfl_xor(ls, o, 64);
        fs += __shfl_xor(fs, o, 64);
        np += __shfl_xor(np, o, 64);
    }
    if (t == 0) {
        float N = (float)np;
        out[0] = ls / N;
        out[1] = lc / N;
        out[2] = fs / N;
    }
}

extern "C" void kernel_launch(void* const* d_in, const int* in_sizes, int n_in,
                              void* d_out, int out_size, void* d_ws, size_t ws_size,
                              hipStream_t stream)
{
    const float* loc_data  = (const float*)d_in[0];
    const float* conf_data = (const float*)d_in[1];
    const float* fc_data   = (const float*)d_in[2];
    const float* loc_t     = (const float*)d_in[3];
    const float* fc_t      = (const float*)d_in[4];
    const int*   conf_t    = (const int*)d_in[5];
    float* out = (float*)d_out;

    float* ce       = (float*)d_ws;
    float* partS    = ce + BP;                   // [NB*PBLK*4] = 8960
    float* partC    = partS + NB * PBLK * 4;     // [NB*PBLK*2] = 4480
    float* loss_c_b = partC + NB * PBLK * 2;     // [64]
    int*   npos_b   = (int*)(loss_c_b + 64);     // [64]
    float* lsum_b   = (float*)(npos_b + 64);     // [64]
    float* fsum_b   = lsum_b + 64;               // [64]

    hipLaunchKernelGGL(k_sl1,  dim3(PBLK, NB), dim3(256), 0, stream,
                       loc_data, fc_data, loc_t, fc_t, conf_t, partS);
    hipLaunchKernelGGL(k_ce,   dim3(PBLK, NB), dim3(256), 0, stream,
                       conf_data, conf_t, ce, partC);
    hipLaunchKernelGGL(k_batch, dim3(NB), dim3(256), 0, stream,
                       ce, conf_t, partS, partC, loss_c_b, npos_b, lsum_b, fsum_b);
    hipLaunchKernelGGL(k_final, dim3(1), dim3(64), 0, stream,
                       loss_c_b, npos_b, lsum_b, fsum_b, out);
}